// Round 1
// baseline (906.229 us; speedup 1.0000x reference)
//
#include <hip/hip_runtime.h>
#include <stdint.h>

typedef float f32x4 __attribute__((ext_vector_type(4)));
typedef short s16x8 __attribute__((ext_vector_type(8)));
typedef short s16x4 __attribute__((ext_vector_type(4)));

#define NSTEPS 499
#define LEN    128
#define HID    512
#define TROW   64000   // 500*128

__device__ __forceinline__ short f2bf_rne(float f) {
  union { float f; uint32_t u; } v; v.f = f;
  uint32_t r = (v.u + 0x7FFFu + ((v.u >> 16) & 1u)) >> 16;
  return (short)(r & 0xFFFFu);
}
__device__ __forceinline__ short f2bf_tr(float f) {
  union { float f; uint32_t u; } v; v.f = f;
  return (short)(v.u >> 16);
}
__device__ __forceinline__ s16x4 pack4(f32x4 v) {
  s16x4 r;
  r[0] = f2bf_tr(v[0]); r[1] = f2bf_tr(v[1]);
  r[2] = f2bf_tr(v[2]); r[3] = f2bf_tr(v[3]);
  return r;
}

// One WG (256 thr = 4 waves) owns 16 batch rows for all 499 steps.
// Transposed MFMA compute: weights = A-fragments (persistent VGPRs),
// activations = B-fragments (LDS, frag-linear layout).
// Frag-linear activation layout: element (batch m, k) lives at
//   shorts offset ((k>>3)*16 + m)*8 + (k&7)
// so a wave's B-frag reads (k = 32s + 8q + i, n=m=lc) are 64 consecutive
// 16B units -> conflict-free contiguous ds_read_b128 bursts.
__global__ __launch_bounds__(256, 1)
void cond_diff_kernel(const float* __restrict__ fd,
                      const float* __restrict__ W1,
                      const float* __restrict__ b1,
                      const float* __restrict__ W2,
                      const float* __restrict__ b2,
                      const float* __restrict__ noise,
                      float* __restrict__ out)
{
  const int tid  = threadIdx.x;
  const int w    = tid >> 6;     // wave 0..3
  const int lane = tid & 63;
  const int q    = lane >> 4;    // quad 0..3
  const int lc   = lane & 15;
  const int bb   = blockIdx.x << 4;   // batch base (16 per WG)

  __shared__ short xbf[16 * 16 * 8];  // x  as bf16, frag-linear (4 KB)
  __shared__ short hbf[64 * 16 * 8];  // h  as bf16, frag-linear (16 KB)

  // ---- persistent weight A-fragments ----
  // Layer1 (D = h^T): wave w owns hidden j in [128w, 128w+128), 8 tiles.
  // A-frag lane mapping: A[m=lc][k=8q+i]; A = W1^T -> element W1[k][jt+lc].
  s16x8 a1[8][4];
#pragma unroll
  for (int t = 0; t < 8; ++t) {
    const int j = 128 * w + 16 * t + lc;
#pragma unroll
    for (int s = 0; s < 4; ++s) {
      s16x8 f;
#pragma unroll
      for (int i = 0; i < 8; ++i)
        f[i] = f2bf_rne(W1[(32 * s + 8 * q + i) * HID + j]);
      a1[t][s] = f;
    }
  }
  // Layer2 (D = s^T): wave w owns out-dim l in [32w, 32w+32), 2 tiles, K=512.
  s16x8 a2[2][16];
#pragma unroll
  for (int u = 0; u < 2; ++u) {
    const int l = 32 * w + 16 * u + lc;
#pragma unroll
    for (int s = 0; s < 16; ++s) {
      s16x8 f;
#pragma unroll
      for (int i = 0; i < 8; ++i)
        f[i] = f2bf_rne(W2[(32 * s + 8 * q + i) * LEN + l]);
      a2[u][s] = f;
    }
  }

  // Biases: C/D layout rows = (lane>>4)*4 + r -> per-lane rows j = 16t+4q+r.
  f32x4 bb1[8], bw1[8];
#pragma unroll
  for (int t = 0; t < 8; ++t) {
    const int j = 128 * w + 16 * t + 4 * q;
    bb1[t] = *(const f32x4*)(b1 + j);                 // b1[j..j+3]
    bw1[t] = *(const f32x4*)(W1 + 128 * HID + j);     // time row of W1
  }
  f32x4 bb2[2];
#pragma unroll
  for (int u = 0; u < 2; ++u)
    bb2[u] = *(const f32x4*)(b2 + 32 * w + 16 * u + 4 * q);

  // ---- x0 = fd[:, 499, :]; fp32 master state in registers ----
  // Ownership (from s^T C/D layout): batch = lc, l = 32w + 16u + 4q + r.
  const int obase = (bb + lc) * TROW;
  f32x4 xm[2];
#pragma unroll
  for (int u = 0; u < 2; ++u) {
    const int l = 32 * w + 16 * u + 4 * q;
    xm[u] = *(const f32x4*)(fd + obase + NSTEPS * LEN + l);
    *(f32x4*)(out + obase + l) = xm[u];               // out[:, 0, :] = x0
    *(s16x4*)(&xbf[((l >> 3) * 16 + lc) * 8 + (l & 7)]) = pack4(xm[u]);
  }
  __syncthreads();

  const float DTc = 0.001f;
  const float SD  = 0.031622776601683794f;  // sqrt(DT)
  const float C0  = 0.9995f;                // 1 - 0.5*DT

#pragma unroll 1
  for (int k = 0; k < NSTEPS; ++k) {
    const float tt = DTc * (float)(NSTEPS - k);   // ts[k]

    // prefetch noise[k] (consumed ~2 MFMA phases later)
    f32x4 eps[2];
#pragma unroll
    for (int u = 0; u < 2; ++u)
      eps[u] = *(const f32x4*)(noise + k * LEN + 32 * w + 16 * u + 4 * q);

    // ---- layer 1: h^T = relu(W1'^T x^T + b1 + t*w1t) ----
    f32x4 acc1[8];
#pragma unroll
    for (int t = 0; t < 8; ++t) acc1[t] = (f32x4){0.f, 0.f, 0.f, 0.f};
#pragma unroll
    for (int s = 0; s < 4; ++s) {
      const s16x8 bf = *(const s16x8*)(&xbf[((4 * s + q) * 16 + lc) * 8]);
#pragma unroll
      for (int t = 0; t < 8; ++t)
        acc1[t] = __builtin_amdgcn_mfma_f32_16x16x32_bf16(a1[t][s], bf, acc1[t], 0, 0, 0);
    }
    // epilogue: lane holds (rows j = 16t+4q+r, col batch=lc); 4 consecutive j
    // -> one ds_write_b64 per tile into frag-linear hbf.
#pragma unroll
    for (int t = 0; t < 8; ++t) {
      f32x4 h;
#pragma unroll
      for (int r = 0; r < 4; ++r)
        h[r] = fmaxf(acc1[t][r] + bb1[t][r] + tt * bw1[t][r], 0.f);
      const int jb = 128 * w + 16 * t + 4 * q;
      *(s16x4*)(&hbf[((jb >> 3) * 16 + lc) * 8 + (jb & 7)]) = pack4(h);
    }
    __syncthreads();

    // ---- layer 2: s^T = W2^T h^T + b2 ----
    f32x4 acc2[2][2];   // 2 partial chains per u for MFMA latency cover
#pragma unroll
    for (int u = 0; u < 2; ++u) {
      acc2[u][0] = (f32x4){0.f, 0.f, 0.f, 0.f};
      acc2[u][1] = (f32x4){0.f, 0.f, 0.f, 0.f};
    }
#pragma unroll
    for (int s = 0; s < 16; ++s) {
      const s16x8 bf = *(const s16x8*)(&hbf[((4 * s + q) * 16 + lc) * 8]);
#pragma unroll
      for (int u = 0; u < 2; ++u)
        acc2[u][s & 1] = __builtin_amdgcn_mfma_f32_16x16x32_bf16(a2[u][s], bf, acc2[u][s & 1], 0, 0, 0);
    }

    // ---- Euler–Maruyama update (fp32), store out[:, 499-k, :] ----
    const int orow = obase + (NSTEPS - k) * LEN;
#pragma unroll
    for (int u = 0; u < 2; ++u) {
      const int l = 32 * w + 16 * u + 4 * q;
      f32x4 xn;
#pragma unroll
      for (int r = 0; r < 4; ++r) {
        const float sc = acc2[u][0][r] + acc2[u][1][r] + bb2[u][r];
        xn[r] = xm[u][r] * C0 - DTc * sc + SD * eps[u][r];
      }
      xm[u] = xn;
      *(f32x4*)(out + orow + l) = xn;
      *(s16x4*)(&xbf[((l >> 3) * 16 + lc) * 8 + (l & 7)]) = pack4(xn);
    }
    __syncthreads();
  }
}

extern "C" void kernel_launch(void* const* d_in, const int* in_sizes, int n_in,
                              void* d_out, int out_size, void* d_ws, size_t ws_size,
                              hipStream_t stream) {
  const float* fd    = (const float*)d_in[0];
  const float* W1    = (const float*)d_in[1];
  const float* b1    = (const float*)d_in[2];
  const float* W2    = (const float*)d_in[3];
  const float* b2    = (const float*)d_in[4];
  const float* noise = (const float*)d_in[5];
  (void)in_sizes; (void)n_in; (void)out_size; (void)d_ws; (void)ws_size;
  cond_diff_kernel<<<dim3(32), dim3(256), 0, stream>>>(fd, W1, b1, W2, b2, noise,
                                                       (float*)d_out);
}

// Round 2
// 777.833 us; speedup vs baseline: 1.1651x; 1.1651x over previous
//
#include <hip/hip_runtime.h>
#include <stdint.h>

typedef float f32x4 __attribute__((ext_vector_type(4)));
typedef short s16x8 __attribute__((ext_vector_type(8)));
typedef short s16x4 __attribute__((ext_vector_type(4)));
typedef unsigned int u32;

#define NSTEPS 499
#define LEN    128
#define HID    512
#define TROW   64000   // 500*128

__device__ __forceinline__ short f2bf_rne(float f) {
  union { float f; u32 u; } v; v.f = f;
  u32 r = (v.u + 0x7FFFu + ((v.u >> 16) & 1u)) >> 16;
  return (short)(r & 0xFFFFu);
}

// pack 4 f32 -> 4 bf16 (round-half-away) with 4 adds + 2 v_perm
__device__ __forceinline__ s16x4 pack4(f32x4 v) {
  union { float f; u32 u; } c0, c1, c2, c3;
  c0.f = v[0]; c1.f = v[1]; c2.f = v[2]; c3.f = v[3];
  u32 u0 = c0.u + 0x8000u, u1 = c1.u + 0x8000u;
  u32 u2 = c2.u + 0x8000u, u3 = c3.u + 0x8000u;
  union { u32 x[2]; s16x4 s; } r;
  r.x[0] = __builtin_amdgcn_perm(u1, u0, 0x07060302u);  // hi16(u1):hi16(u0)
  r.x[1] = __builtin_amdgcn_perm(u3, u2, 0x07060302u);
  return r.s;
}

// One WG = 512 thr = 8 waves = 2 waves/SIMD owns 16 batch rows for all steps.
// Layer1: wave w owns hidden j in [64w, 64w+64) (4 tiles), full K=128.
// Layer2: wave w owns l-tile To=w with K-half kh=w&1; partner w^1 has the
//         other K-half; partials exchanged via LDS (1 b128 each way).
// Frag-linear activation layout: element (batch m, k) at shorts offset
//   ((k>>3)*16 + m)*8 + (k&7)  -> wave B-frag reads are contiguous 1KB bursts.
__global__ __launch_bounds__(512, 2)
void cond_diff_kernel(const float* __restrict__ fd,
                      const float* __restrict__ W1,
                      const float* __restrict__ b1,
                      const float* __restrict__ W2,
                      const float* __restrict__ b2,
                      const float* __restrict__ noise,
                      float* __restrict__ out)
{
  const int tid  = threadIdx.x;
  const int w    = tid >> 6;     // wave 0..7
  const int lane = tid & 63;
  const int q    = lane >> 4;    // quad 0..3
  const int lc   = lane & 15;
  const int bb   = blockIdx.x << 4;

  __shared__ short xbf[16 * 16 * 8];       // x  bf16 frag-linear, 4 KB
  __shared__ short hbf[64 * 16 * 8];       // h  bf16 frag-linear, 16 KB
  __shared__ float pscr[8 * 4 * 16 * 4];   // layer2 fp32 partials, 8 KB

  const int kh = w & 1;          // layer2 K-half
  const int To = w;              // owned l-tile
  const int Tf = w ^ 1;          // partner's l-tile

  // ---- layer1 weight A-frags: A[m=lc][k=8q+i] = W1[k][j] ----
  s16x8 a1[4][4];
#pragma unroll
  for (int t = 0; t < 4; ++t) {
    const int j = 64 * w + 16 * t + lc;
#pragma unroll
    for (int s = 0; s < 4; ++s) {
      s16x8 f;
#pragma unroll
      for (int i = 0; i < 8; ++i)
        f[i] = f2bf_rne(W1[(32 * s + 8 * q + i) * HID + j]);
      a1[t][s] = f;
    }
  }
  // ---- layer2 weight A-frags (own + foreign tile, K-half kh) ----
  s16x8 a2o[8], a2f[8];
#pragma unroll
  for (int s8 = 0; s8 < 8; ++s8) {
    const int kb = 256 * kh + 32 * s8 + 8 * q;
    s16x8 fo, ff;
#pragma unroll
    for (int i = 0; i < 8; ++i) {
      fo[i] = f2bf_rne(W2[(kb + i) * LEN + 16 * To + lc]);
      ff[i] = f2bf_rne(W2[(kb + i) * LEN + 16 * Tf + lc]);
    }
    a2o[s8] = fo; a2f[s8] = ff;
  }

  // ---- biases in C/D layout (rows j0+r, col lc) ----
  f32x4 bb1[4], bw1[4];
#pragma unroll
  for (int t = 0; t < 4; ++t) {
    const int j0 = 64 * w + 16 * t + 4 * q;
    bb1[t] = *(const f32x4*)(b1 + j0);
    bw1[t] = *(const f32x4*)(W1 + 128 * HID + j0);   // time row of W1
  }
  const int l0 = 16 * w + 4 * q;
  f32x4 nb2;
  {
    f32x4 b2v = *(const f32x4*)(b2 + l0);
#pragma unroll
    for (int r = 0; r < 4; ++r) nb2[r] = -0.001f * b2v[r];
  }

  // ---- x0 = fd[:, 499, :]; fp32 master state (rows l0+r, col batch=lc) ----
  const int obase = (bb + lc) * TROW;
  f32x4 xm = *(const f32x4*)(fd + obase + NSTEPS * LEN + l0);
  *(f32x4*)(out + obase + l0) = xm;                 // out[:, 0, :] = x0
  *(s16x4*)(&xbf[((l0 >> 3) * 16 + lc) * 8 + (l0 & 7)]) = pack4(xm);
  __syncthreads();

  const float DTc = 0.001f;
  const float SD  = 0.031622776601683794f;  // sqrt(DT)
  const float C0  = 0.9995f;                // 1 - 0.5*DT

#pragma unroll 1
  for (int k = 0; k < NSTEPS; ++k) {
    const float tt = DTc * (float)(NSTEPS - k);

    f32x4 eps = *(const f32x4*)(noise + k * LEN + l0);  // prefetch

    // ---- layer 1: h = relu(W1^T x^T + (b1 + t*w1t)) ; bias in acc init ----
    f32x4 acc1[4];
#pragma unroll
    for (int t = 0; t < 4; ++t)
#pragma unroll
      for (int r = 0; r < 4; ++r)
        acc1[t][r] = __builtin_fmaf(tt, bw1[t][r], bb1[t][r]);
#pragma unroll
    for (int s = 0; s < 4; ++s) {
      const s16x8 bf = *(const s16x8*)(&xbf[((4 * s + q) * 16 + lc) * 8]);
#pragma unroll
      for (int t = 0; t < 4; ++t)
        acc1[t] = __builtin_amdgcn_mfma_f32_16x16x32_bf16(a1[t][s], bf, acc1[t], 0, 0, 0);
    }
#pragma unroll
    for (int t = 0; t < 4; ++t) {
      f32x4 h;
#pragma unroll
      for (int r = 0; r < 4; ++r) h[r] = fmaxf(acc1[t][r], 0.f);
      const int jb = 64 * w + 16 * t + 4 * q;
      *(s16x4*)(&hbf[((jb >> 3) * 16 + lc) * 8 + (jb & 7)]) = pack4(h);
    }
    __syncthreads();   // publish h

    // ---- layer 2 partial: tiles {To, Tf} over K-half kh ----
    f32x4 accO = (f32x4){0.f, 0.f, 0.f, 0.f};
    f32x4 accF = (f32x4){0.f, 0.f, 0.f, 0.f};
#pragma unroll
    for (int s8 = 0; s8 < 8; ++s8) {
      const int s = 8 * kh + s8;
      const s16x8 bf = *(const s16x8*)(&hbf[((4 * s + q) * 16 + lc) * 8]);
      accO = __builtin_amdgcn_mfma_f32_16x16x32_bf16(a2o[s8], bf, accO, 0, 0, 0);
      accF = __builtin_amdgcn_mfma_f32_16x16x32_bf16(a2f[s8], bf, accF, 0, 0, 0);
    }
    *(f32x4*)(&pscr[((Tf * 4 + q) * 16 + lc) * 4]) = accF;
    __syncthreads();   // publish partials
    const f32x4 po = *(const f32x4*)(&pscr[((To * 4 + q) * 16 + lc) * 4]);

    // ---- Euler–Maruyama update (fp32), store out[:, 499-k, :] ----
    const int orow = obase + (NSTEPS - k) * LEN;
    f32x4 xn;
#pragma unroll
    for (int r = 0; r < 4; ++r) {
      const float sc = accO[r] + po[r];
      const float t1 = __builtin_fmaf(SD, eps[r], nb2[r]);
      const float t2 = __builtin_fmaf(-DTc, sc, t1);
      xn[r] = __builtin_fmaf(C0, xm[r], t2);
    }
    xm = xn;
    *(f32x4*)(out + orow + l0) = xn;
    *(s16x4*)(&xbf[((l0 >> 3) * 16 + lc) * 8 + (l0 & 7)]) = pack4(xn);
    __syncthreads();   // publish x
  }
}

extern "C" void kernel_launch(void* const* d_in, const int* in_sizes, int n_in,
                              void* d_out, int out_size, void* d_ws, size_t ws_size,
                              hipStream_t stream) {
  const float* fd    = (const float*)d_in[0];
  const float* W1    = (const float*)d_in[1];
  const float* b1    = (const float*)d_in[2];
  const float* W2    = (const float*)d_in[3];
  const float* b2    = (const float*)d_in[4];
  const float* noise = (const float*)d_in[5];
  (void)in_sizes; (void)n_in; (void)out_size; (void)d_ws; (void)ws_size;
  cond_diff_kernel<<<dim3(32), dim3(512), 0, stream>>>(fd, W1, b1, W2, b2, noise,
                                                       (float*)d_out);
}

// Round 3
// 745.634 us; speedup vs baseline: 1.2154x; 1.0432x over previous
//
#include <hip/hip_runtime.h>
#include <stdint.h>

typedef float f32x4 __attribute__((ext_vector_type(4)));
typedef short s16x8 __attribute__((ext_vector_type(8)));
typedef short s16x4 __attribute__((ext_vector_type(4)));
typedef unsigned int u32;

#define NSTEPS 499
#define LEN    128
#define HID    512
#define TROW   64000   // 500*128

union frag8 { s16x8 v; u32 u[4]; };
union fvec4 { f32x4 v; float f[4]; };

// Opaque register pin: value becomes asm output -> cannot be rematerialized
// or sunk into the loop; must stay live in VGPRs.
#define PIN_FRAG(fr) asm volatile("" : "+v"((fr).u[0]), "+v"((fr).u[1]), \
                                       "+v"((fr).u[2]), "+v"((fr).u[3]))
#define PIN_F4(fv)   asm volatile("" : "+v"((fv).f[0]), "+v"((fv).f[1]), \
                                       "+v"((fv).f[2]), "+v"((fv).f[3]))

__device__ __forceinline__ short f2bf_rne(float f) {
  union { float f; u32 u; } v; v.f = f;
  u32 r = (v.u + 0x7FFFu + ((v.u >> 16) & 1u)) >> 16;
  return (short)(r & 0xFFFFu);
}

// pack 4 f32 -> 4 bf16 (round-half-away) with 4 adds + 2 v_perm
__device__ __forceinline__ s16x4 pack4(f32x4 v) {
  union { float f; u32 u; } c0, c1, c2, c3;
  c0.f = v[0]; c1.f = v[1]; c2.f = v[2]; c3.f = v[3];
  u32 u0 = c0.u + 0x8000u, u1 = c1.u + 0x8000u;
  u32 u2 = c2.u + 0x8000u, u3 = c3.u + 0x8000u;
  union { u32 x[2]; s16x4 s; } r;
  r.x[0] = __builtin_amdgcn_perm(u1, u0, 0x07060302u);
  r.x[1] = __builtin_amdgcn_perm(u3, u2, 0x07060302u);
  return r.s;
}

// One WG = 512 thr = 8 waves = 2 waves/SIMD owns 16 batch rows for all steps.
// Weights live PINNED in VGPRs (128 regs/lane). Activations go through LDS
// in frag-linear layout: element (batch m, k) at shorts offset
//   ((k>>3)*16 + m)*8 + (k&7)  -> wave B-frag reads are contiguous 1KB bursts.
__global__ __launch_bounds__(512, 2)
void cond_diff_kernel(const float* __restrict__ fd,
                      const float* __restrict__ W1,
                      const float* __restrict__ b1,
                      const float* __restrict__ W2,
                      const float* __restrict__ b2,
                      const float* __restrict__ noise,
                      float* __restrict__ out)
{
  const int tid  = threadIdx.x;
  const int w    = tid >> 6;     // wave 0..7
  const int lane = tid & 63;
  const int q    = lane >> 4;    // quad 0..3
  const int lc   = lane & 15;
  const int bb   = blockIdx.x << 4;

  __shared__ short xbf[16 * 16 * 8];       // x  bf16 frag-linear, 4 KB
  __shared__ short hbf[64 * 16 * 8];       // h  bf16 frag-linear, 16 KB
  __shared__ float pscr[8 * 4 * 16 * 4];   // layer2 fp32 partials, 8 KB

  const int kh = w & 1;          // layer2 K-half
  const int To = w;              // owned l-tile
  const int Tf = w ^ 1;          // partner's l-tile

  // ---- layer1 weight A-frags: A[m=lc][k=8q+i] = W1[k][j], PINNED ----
  frag8 a1[4][4];
#pragma unroll
  for (int t = 0; t < 4; ++t) {
    const int j = 64 * w + 16 * t + lc;
#pragma unroll
    for (int s = 0; s < 4; ++s) {
      s16x8 f;
#pragma unroll
      for (int i = 0; i < 8; ++i)
        f[i] = f2bf_rne(W1[(32 * s + 8 * q + i) * HID + j]);
      a1[t][s].v = f;
      PIN_FRAG(a1[t][s]);
    }
  }
  // ---- layer2 weight A-frags (own + foreign tile, K-half kh), PINNED ----
  frag8 a2o[8], a2f[8];
#pragma unroll
  for (int s8 = 0; s8 < 8; ++s8) {
    const int kb = 256 * kh + 32 * s8 + 8 * q;
    s16x8 fo, ff;
#pragma unroll
    for (int i = 0; i < 8; ++i) {
      fo[i] = f2bf_rne(W2[(kb + i) * LEN + 16 * To + lc]);
      ff[i] = f2bf_rne(W2[(kb + i) * LEN + 16 * Tf + lc]);
    }
    a2o[s8].v = fo; a2f[s8].v = ff;
    PIN_FRAG(a2o[s8]); PIN_FRAG(a2f[s8]);
  }

  // ---- biases in C/D layout (rows j0+r, col lc), PINNED ----
  fvec4 bb1[4], bw1[4];
#pragma unroll
  for (int t = 0; t < 4; ++t) {
    const int j0 = 64 * w + 16 * t + 4 * q;
    bb1[t].v = *(const f32x4*)(b1 + j0);
    bw1[t].v = *(const f32x4*)(W1 + 128 * HID + j0);   // time row of W1
    PIN_F4(bb1[t]); PIN_F4(bw1[t]);
  }
  const int l0 = 16 * w + 4 * q;
  fvec4 nb2;
  {
    f32x4 b2v = *(const f32x4*)(b2 + l0);
#pragma unroll
    for (int r = 0; r < 4; ++r) nb2.f[r] = -0.001f * b2v[r];
    PIN_F4(nb2);
  }

  // ---- x0 = fd[:, 499, :]; fp32 master state (rows l0+r, col batch=lc) ----
  const int obase = (bb + lc) * TROW;
  f32x4 xm = *(const f32x4*)(fd + obase + NSTEPS * LEN + l0);
  *(f32x4*)(out + obase + l0) = xm;                 // out[:, 0, :] = x0
  *(s16x4*)(&xbf[((l0 >> 3) * 16 + lc) * 8 + (l0 & 7)]) = pack4(xm);
  __syncthreads();

  const float DTc = 0.001f;
  const float SD  = 0.031622776601683794f;  // sqrt(DT)
  const float C0  = 0.9995f;                // 1 - 0.5*DT

#pragma unroll 1
  for (int k = 0; k < NSTEPS; ++k) {
    const float tt = DTc * (float)(NSTEPS - k);

    f32x4 eps = *(const f32x4*)(noise + k * LEN + l0);  // prefetch

    // ---- layer 1: h = relu(W1^T x^T + (b1 + t*w1t)) ; bias in acc init ----
    f32x4 acc1[4];
#pragma unroll
    for (int t = 0; t < 4; ++t)
#pragma unroll
      for (int r = 0; r < 4; ++r)
        acc1[t][r] = __builtin_fmaf(tt, bw1[t].f[r], bb1[t].f[r]);
#pragma unroll
    for (int s = 0; s < 4; ++s) {
      const s16x8 bf = *(const s16x8*)(&xbf[((4 * s + q) * 16 + lc) * 8]);
#pragma unroll
      for (int t = 0; t < 4; ++t)
        acc1[t] = __builtin_amdgcn_mfma_f32_16x16x32_bf16(a1[t][s].v, bf, acc1[t], 0, 0, 0);
    }
#pragma unroll
    for (int t = 0; t < 4; ++t) {
      f32x4 h;
#pragma unroll
      for (int r = 0; r < 4; ++r) h[r] = fmaxf(acc1[t][r], 0.f);
      const int jb = 64 * w + 16 * t + 4 * q;
      *(s16x4*)(&hbf[((jb >> 3) * 16 + lc) * 8 + (jb & 7)]) = pack4(h);
    }
    __syncthreads();   // publish h

    // ---- layer 2 partial: tiles {To, Tf} over K-half kh ----
    f32x4 accO = (f32x4){0.f, 0.f, 0.f, 0.f};
    f32x4 accF = (f32x4){0.f, 0.f, 0.f, 0.f};
#pragma unroll
    for (int s8 = 0; s8 < 8; ++s8) {
      const int s = 8 * kh + s8;
      const s16x8 bf = *(const s16x8*)(&hbf[((4 * s + q) * 16 + lc) * 8]);
      accO = __builtin_amdgcn_mfma_f32_16x16x32_bf16(a2o[s8].v, bf, accO, 0, 0, 0);
      accF = __builtin_amdgcn_mfma_f32_16x16x32_bf16(a2f[s8].v, bf, accF, 0, 0, 0);
    }
    *(f32x4*)(&pscr[((Tf * 4 + q) * 16 + lc) * 4]) = accF;
    __syncthreads();   // publish partials
    const f32x4 po = *(const f32x4*)(&pscr[((To * 4 + q) * 16 + lc) * 4]);

    // ---- Euler–Maruyama update (fp32), store out[:, 499-k, :] ----
    const int orow = obase + (NSTEPS - k) * LEN;
    f32x4 xn;
#pragma unroll
    for (int r = 0; r < 4; ++r) {
      const float sc = accO[r] + po[r];
      const float t1 = __builtin_fmaf(SD, eps[r], nb2.f[r]);
      const float t2 = __builtin_fmaf(-DTc, sc, t1);
      xn[r] = __builtin_fmaf(C0, xm[r], t2);
    }
    xm = xn;
    *(f32x4*)(out + orow + l0) = xn;
    *(s16x4*)(&xbf[((l0 >> 3) * 16 + lc) * 8 + (l0 & 7)]) = pack4(xn);
    __syncthreads();   // publish x
  }
}

extern "C" void kernel_launch(void* const* d_in, const int* in_sizes, int n_in,
                              void* d_out, int out_size, void* d_ws, size_t ws_size,
                              hipStream_t stream) {
  const float* fd    = (const float*)d_in[0];
  const float* W1    = (const float*)d_in[1];
  const float* b1    = (const float*)d_in[2];
  const float* W2    = (const float*)d_in[3];
  const float* b2    = (const float*)d_in[4];
  const float* noise = (const float*)d_in[5];
  (void)in_sizes; (void)n_in; (void)out_size; (void)d_ws; (void)ws_size;
  cond_diff_kernel<<<dim3(32), dim3(512), 0, stream>>>(fd, W1, b1, W2, b2, noise,
                                                       (float*)d_out);
}